// Round 2
// baseline (134.078 us; speedup 1.0000x reference)
//
#include <hip/hip_runtime.h>

// Chamfer NN squared distances, single-pass pair-sharing version.
// Each unique (n,m) pair is computed ONCE; it updates both the n-row min
// (dist1) and the m-col min (dist2).
//
// Block: owns TN=32 query points (rows) of batch b, held in registers
// (QN=8 per thread across 4 ty-groups); sweeps all M reference points in
// LDS tiles of TM=128. The 4 waves split m-columns, so col-min reduction
// is in-wave (shfl over ty only); dist2 partials combined via atomicMin.
// dist1 is complete per block -> plain store.

constexpr int TPB  = 256;
constexpr int QN   = 8;         // rows per thread
constexpr int TN   = 4 * QN;    // 32 rows per block (4 ty-groups)
constexpr int QM   = 2;         // cols per thread per tile
constexpr int NCOL = 64;        // 4 waves * 16 tx
constexpr int TM   = NCOL * QM; // 128 cols per LDS tile

__global__ __launch_bounds__(TPB, 4) void nnd_tile(
    const float* __restrict__ p1, const float* __restrict__ p2,
    float* __restrict__ out, int B, int N, int M)
{
    const int b    = blockIdx.y;
    const int n0   = blockIdx.x * TN;
    const int tid  = threadIdx.x;
    const int lane = tid & 63;
    const int w    = tid >> 6;       // wave 0..3
    const int tx   = lane & 15;      // col subgroup
    const int ty   = lane >> 4;      // row group 0..3
    const int col  = (w << 4) | tx;  // 0..63

    const float* __restrict__ q = p1 + (size_t)b * N * 3;
    const float* __restrict__ r = p2 + (size_t)b * M * 3;
    float* __restrict__ d1 = out + (size_t)b * N;
    float* __restrict__ d2 = out + (size_t)B * N + (size_t)b * M;

    // load this thread's QN query points into registers
    float nx[QN], ny[QN], nz[QN], rm[QN];
#pragma unroll
    for (int i = 0; i < QN; ++i) {
        const int n = n0 + ty * QN + i;
        if (n < N) { nx[i] = q[n*3+0]; ny[i] = q[n*3+1]; nz[i] = q[n*3+2]; }
        else       { nx[i] = 1e30f;    ny[i] = 1e30f;    nz[i] = 1e30f;    }
        rm[i] = 3.0e38f;
    }

    __shared__ float4 shm[TM];
    __shared__ float  red[4][TN];

    for (int ts = 0; ts < M; ts += TM) {
        __syncthreads();  // previous tile fully consumed
        if (ts + TM <= M) {
            // full tile: threads 0..63 stage 2 points each via float2 loads
            if (tid < TM / 2) {
                const float2* src = (const float2*)(r + (size_t)ts * 3);
                float2 a = src[3 * tid + 0];
                float2 c = src[3 * tid + 1];
                float2 e = src[3 * tid + 2];
                shm[2 * tid + 0] = make_float4(a.x, a.y, c.x, 0.f);
                shm[2 * tid + 1] = make_float4(c.y, e.x, e.y, 0.f);
            }
        } else {
            // ragged tail: guarded scalar path, pad with far points
            if (tid < TM) {
                float4 v = make_float4(1e30f, 1e30f, 1e30f, 0.f);
                if (ts + tid < M) {
                    const float* pp = r + (size_t)(ts + tid) * 3;
                    v = make_float4(pp[0], pp[1], pp[2], 0.f);
                }
                shm[tid] = v;
            }
        }
        __syncthreads();

        const float4 mp0 = shm[col * QM + 0];
        const float4 mp1 = shm[col * QM + 1];
        float cm0 = 3.0e38f, cm1 = 3.0e38f;
#pragma unroll
        for (int i = 0; i < QN; ++i) {
            float dx = nx[i] - mp0.x, dy = ny[i] - mp0.y, dz = nz[i] - mp0.z;
            float d  = dx * dx; d = fmaf(dy, dy, d); d = fmaf(dz, dz, d);
            rm[i] = fminf(rm[i], d);
            cm0   = fminf(cm0, d);
            float ex = nx[i] - mp1.x, ey = ny[i] - mp1.y, ez = nz[i] - mp1.z;
            float e  = ex * ex; e = fmaf(ey, ey, e); e = fmaf(ez, ez, e);
            rm[i] = fminf(rm[i], e);
            cm1   = fminf(cm1, e);
        }
        // col-min: reduce over the 4 ty groups (in-wave butterfly)
        cm0 = fminf(cm0, __shfl_xor(cm0, 16));
        cm0 = fminf(cm0, __shfl_xor(cm0, 32));
        cm1 = fminf(cm1, __shfl_xor(cm1, 16));
        cm1 = fminf(cm1, __shfl_xor(cm1, 32));
        if (ty == 0) {
            const int m = ts + col * QM;
            if (m     < M) atomicMin((int*)&d2[m],     __float_as_int(cm0));
            if (m + 1 < M) atomicMin((int*)&d2[m + 1], __float_as_int(cm1));
        }
    }

    // row-min: butterfly over the 16 tx lanes (in-wave), then combine 4 waves
#pragma unroll
    for (int i = 0; i < QN; ++i) {
        float v = rm[i];
        v = fminf(v, __shfl_xor(v, 1));
        v = fminf(v, __shfl_xor(v, 2));
        v = fminf(v, __shfl_xor(v, 4));
        v = fminf(v, __shfl_xor(v, 8));
        rm[i] = v;
    }
    __syncthreads();
    if (tx == 0) {
#pragma unroll
        for (int i = 0; i < QN; ++i) red[w][ty * QN + i] = rm[i];
    }
    __syncthreads();
    if (tid < TN) {
        const float v = fminf(fminf(red[0][tid], red[1][tid]),
                              fminf(red[2][tid], red[3][tid]));
        const int n = n0 + tid;
        if (n < N) d1[n] = v;
    }
}

extern "C" void kernel_launch(void* const* d_in, const int* in_sizes, int n_in,
                              void* d_out, int out_size, void* d_ws, size_t ws_size,
                              hipStream_t stream) {
    const float* p1 = (const float*)d_in[0];
    const float* p2 = (const float*)d_in[1];
    float* out = (float*)d_out;

    const int B = 16;
    const int N = in_sizes[0] / (B * 3);
    const int M = in_sizes[1] / (B * 3);

    // init all outputs to large positive float (0x7f7f7f7f ~ 3.39e38):
    // dist2 needs it for atomicMin; dist1 region is overwritten by stores.
    hipMemsetAsync(d_out, 0x7f, (size_t)out_size * sizeof(float), stream);

    dim3 grid((N + TN - 1) / TN, B);
    nnd_tile<<<grid, TPB, 0, stream>>>(p1, p2, out, B, N, M);
}

// Round 3
// 53.346 us; speedup vs baseline: 2.5134x; 2.5134x over previous
//
#include <hip/hip_runtime.h>

// Chamfer NN squared distances — identity-folded, direction-split version.
//
// d(q,r) = |q|^2 + |r|^2 - 2 q.r  (the reference's own formulation).
// Stage refs in LDS as (-2x, -2y, -2z, |r|^2); per pair the distance
// (minus the |q|^2 constant) is 3 fma + 1 min. |q|^2 is added after the
// slice-min, before the atomic combine (min is translation-invariant).
//
// Each thread owns IPT=4 query points; each block owns one 512-ref slice
// (SPLIT=8 slices per direction) staged to LDS once. Partial minima are
// combined with atomicMin on the int view (distances >= 0).

constexpr int TPB   = 256;  // 4 waves
constexpr int IPT   = 4;    // query points per thread
constexpr int TILE  = 512;  // refs staged per block slice
constexpr int SPLIT = 8;    // reference-dim split factor

__global__ __launch_bounds__(TPB, 4) void nnd_fold(
    const float* __restrict__ p1, const float* __restrict__ p2,
    float* __restrict__ out, int B, int N, int M)
{
    const int z   = blockIdx.z;
    const int dir = z / SPLIT;   // 0: queries=p1 refs=p2 (dist1); 1: swapped
    const int s   = z % SPLIT;
    const int b   = blockIdx.y;

    const float* __restrict__ q = dir ? p2 : p1;
    const float* __restrict__ r = dir ? p1 : p2;
    const int Nq = dir ? M : N;
    const int Nr = dir ? N : M;
    float* __restrict__ o = out + (dir ? (size_t)B * N : 0) + (size_t)b * Nq;

    const int tid = threadIdx.x;

    // load this thread's IPT query points + |q|^2 into registers
    const float* qb = q + (size_t)b * Nq * 3;
    float qx[IPT], qy[IPT], qz[IPT], qs[IPT], mn[IPT];
    int   qi[IPT];
#pragma unroll
    for (int i = 0; i < IPT; ++i) {
        qi[i] = blockIdx.x * (TPB * IPT) + i * TPB + tid;
        if (qi[i] < Nq) {
            qx[i] = qb[qi[i] * 3 + 0];
            qy[i] = qb[qi[i] * 3 + 1];
            qz[i] = qb[qi[i] * 3 + 2];
        } else {
            qx[i] = qy[i] = qz[i] = 0.f;
        }
        float sq = qx[i] * qx[i];
        sq = fmaf(qy[i], qy[i], sq);
        sq = fmaf(qz[i], qz[i], sq);
        qs[i] = sq;
        mn[i] = 3.0e38f;
    }

    // this block's reference slice
    const int per = (Nr + SPLIT - 1) / SPLIT;
    const int r0  = s * per;
    const int r1  = min(Nr, r0 + per);

    __shared__ float4 shm[TILE];
    const float* rb = r + (size_t)b * Nr * 3;

    for (int ts = r0; ts < r1; ts += TILE) {
        const int npts = min(TILE, r1 - ts);
        __syncthreads();
        if (npts == TILE && ((((size_t)b * Nr + (size_t)ts) * 3) & 1) == 0) {
            // fast path: full tile, float2-aligned source; 2 points/thread
            const float2* src = (const float2*)(rb + (size_t)ts * 3);
            float2 a = src[3 * tid + 0];
            float2 c = src[3 * tid + 1];
            float2 e = src[3 * tid + 2];
            float s0 = a.x * a.x; s0 = fmaf(a.y, a.y, s0); s0 = fmaf(c.x, c.x, s0);
            float s1 = c.y * c.y; s1 = fmaf(e.x, e.x, s1); s1 = fmaf(e.y, e.y, s1);
            shm[2 * tid + 0] = make_float4(-2.f * a.x, -2.f * a.y, -2.f * c.x, s0);
            shm[2 * tid + 1] = make_float4(-2.f * c.y, -2.f * e.x, -2.f * e.y, s1);
        } else {
            // ragged path: guarded scalar loads; pad with min-neutral entries
#pragma unroll
            for (int k = 0; k < 2; ++k) {
                const int pl = 2 * tid + k;
                float4 v = make_float4(0.f, 0.f, 0.f, 3.0e38f);
                if (pl < npts) {
                    const float* pp = rb + (size_t)(ts + pl) * 3;
                    float sq = pp[0] * pp[0];
                    sq = fmaf(pp[1], pp[1], sq);
                    sq = fmaf(pp[2], pp[2], sq);
                    v = make_float4(-2.f * pp[0], -2.f * pp[1], -2.f * pp[2], sq);
                }
                shm[pl] = v;
            }
        }
        __syncthreads();

#pragma unroll 8
        for (int j = 0; j < TILE; ++j) {
            const float4 p = shm[j];   // uniform address -> broadcast, conflict-free
#pragma unroll
            for (int i = 0; i < IPT; ++i) {
                float t = fmaf(p.x, qx[i], p.w);
                t = fmaf(p.y, qy[i], t);
                t = fmaf(p.z, qz[i], t);
                mn[i] = fminf(mn[i], t);
            }
        }
    }

    // combine slice partials; distances >= 0 so int order == float order
#pragma unroll
    for (int i = 0; i < IPT; ++i) {
        if (qi[i] < Nq) atomicMin((int*)&o[qi[i]], __float_as_int(mn[i] + qs[i]));
    }
}

extern "C" void kernel_launch(void* const* d_in, const int* in_sizes, int n_in,
                              void* d_out, int out_size, void* d_ws, size_t ws_size,
                              hipStream_t stream) {
    const float* p1 = (const float*)d_in[0];
    const float* p2 = (const float*)d_in[1];
    float* out = (float*)d_out;

    const int B = 16;
    const int N = in_sizes[0] / (B * 3);
    const int M = in_sizes[1] / (B * 3);

    // init outputs to large positive float (0x7f7f7f7f ~ 3.39e38) for atomicMin
    hipMemsetAsync(d_out, 0x7f, (size_t)out_size * sizeof(float), stream);

    const int qmax    = (N > M) ? N : M;
    const int qblocks = (qmax + TPB * IPT - 1) / (TPB * IPT);
    dim3 grid(qblocks, B, 2 * SPLIT);
    nnd_fold<<<grid, TPB, 0, stream>>>(p1, p2, out, B, N, M);
}

// Round 4
// 35.910 us; speedup vs baseline: 3.7337x; 1.4855x over previous
//
#include <hip/hip_runtime.h>

// Chamfer NN squared distances via MFMA (f16 hi/lo emulation).
//
// d(q,r) = |q|^2 + |r|^2 - 2 q.r packed into ONE mfma_f32_32x32x16_f16:
// K-slots (A-content, B-content):
//   k0-2:  (-2*h(q), h(r))   per coord x,y,z
//   k3-5:  (-2*h(q), l(r))
//   k6-8:  (-2*l(q), h(r))
//   k9-10: (1, hi/lo(|r|^2))
//   k11-12:(hi/lo(|q|^2), 1)
//   k13-15: 0
// where h(x)=f16(x), l(x)=f16(x-h(x)). MFMA C-in = 0, so D = squared
// distance (error ~1e-4). Epilogue: 1 v_min per pair, cross-lane shfl
// reduce over the 32 columns, direct store. No atomics.
//
// A/B fragments are precomputed (pack_pts) into d_ws as 32 B/point in the
// lane-group K order (k = (lane>>5)*8 + j); A and B share the same k-map
// so the dot pairing is robust to the exact HW permutation.

typedef _Float16 v8h  __attribute__((ext_vector_type(8)));
typedef float    v16f __attribute__((ext_vector_type(16)));

constexpr int MTPB  = 256;   // 4 waves
constexpr int RPB   = 128;   // rows per block = 4 waves x 32
constexpr int CHUNK = 1024;  // ref cols per LDS chunk (32 KB)

__global__ void pack_pts(const float* __restrict__ p1, const float* __restrict__ p2,
                         uint4* __restrict__ ws, int n1, int n2)
{
    const int gid = blockIdx.x * blockDim.x + threadIdx.x;
    if (gid >= n1 + n2) return;
    const float* src;
    int pi;
    uint4 *Adst, *Bdst;
    // ws layout (uint4 units, 2 per point): P1A | P1B | P2A | P2B
    if (gid < n1) { src = p1; pi = gid;
                    Adst = ws;                              Bdst = ws + 2 * (size_t)n1; }
    else          { src = p2; pi = gid - n1;
                    Adst = ws + 4 * (size_t)n1;             Bdst = ws + 4 * (size_t)n1 + 2 * (size_t)n2; }

    const float x = src[(size_t)pi * 3 + 0];
    const float y = src[(size_t)pi * 3 + 1];
    const float z = src[(size_t)pi * 3 + 2];
    const float s = fmaf(z, z, fmaf(y, y, x * x));

    const _Float16 hx = (_Float16)x, hy = (_Float16)y, hz = (_Float16)z;
    const _Float16 lx = (_Float16)(x - (float)hx);
    const _Float16 ly = (_Float16)(y - (float)hy);
    const _Float16 lz = (_Float16)(z - (float)hz);
    const _Float16 sh = (_Float16)s;
    const _Float16 sl = (_Float16)(s - (float)sh);
    // -2*h == f16(-2x) exactly (power-of-2 scale), keeps A/B splits consistent
    const _Float16 nhx = (_Float16)(-2.f * x);
    const _Float16 nhy = (_Float16)(-2.f * y);
    const _Float16 nhz = (_Float16)(-2.f * z);
    const _Float16 nlx = (_Float16)(-2.f * (x - (float)hx));
    const _Float16 nly = (_Float16)(-2.f * (y - (float)hy));
    const _Float16 nlz = (_Float16)(-2.f * (z - (float)hz));
    const _Float16 one = (_Float16)1.f, zz = (_Float16)0.f;

    const v8h A0 = {nhx, nhy, nhz, nhx, nhy, nhz, nlx, nly};
    const v8h A1 = {nlz, one, one, sh,  sl,  zz,  zz,  zz };
    const v8h B0 = {hx,  hy,  hz,  lx,  ly,  lz,  hx,  hy };
    const v8h B1 = {hz,  sh,  sl,  one, one, zz,  zz,  zz };

    Adst[(size_t)pi * 2 + 0] = __builtin_bit_cast(uint4, A0);
    Adst[(size_t)pi * 2 + 1] = __builtin_bit_cast(uint4, A1);
    Bdst[(size_t)pi * 2 + 0] = __builtin_bit_cast(uint4, B0);
    Bdst[(size_t)pi * 2 + 1] = __builtin_bit_cast(uint4, B1);
}

__global__ __launch_bounds__(MTPB, 4) void nnd_mfma(
    const uint4* __restrict__ ws, float* __restrict__ out, int B, int N, int M)
{
    const int dir = blockIdx.z;        // 0: q=p1,r=p2 (dist1); 1: swapped
    const int b   = blockIdx.y;
    const size_t n1 = (size_t)B * N, n2 = (size_t)B * M;
    const uint4* Ap; const uint4* Bp; float* o; int Nq, Nr;
    if (dir == 0) { Ap = ws;            Bp = ws + 4 * n1 + 2 * n2; o = out;      Nq = N; Nr = M; }
    else          { Ap = ws + 4 * n1;   Bp = ws + 2 * n1;          o = out + n1; Nq = M; Nr = N; }

    const int tid  = threadIdx.x;
    const int w    = tid >> 6;
    const int lane = tid & 63;
    const int c    = lane & 31;   // MFMA row (A) / col (B) within tile
    const int g    = lane >> 5;   // k-group
    const int row0 = blockIdx.x * RPB + w * 32;

    const v8h a = __builtin_bit_cast(v8h, Ap[((size_t)b * Nq + row0 + c) * 2 + g]);
    v16f zc;
#pragma unroll
    for (int r = 0; r < 16; ++r) zc[r] = 0.f;
    float rm[16];
#pragma unroll
    for (int r = 0; r < 16; ++r) rm[r] = 3.0e38f;

    __shared__ uint4 sb[CHUNK * 2];
    const uint4* bsrc = Bp + (size_t)b * Nr * 2;

    for (int ch = 0; ch < Nr; ch += CHUNK) {
        __syncthreads();
#pragma unroll
        for (int i = 0; i < (CHUNK * 2) / MTPB; ++i)
            sb[tid + i * MTPB] = bsrc[(size_t)ch * 2 + tid + i * MTPB];
        __syncthreads();
#pragma unroll 4
        for (int st = 0; st < CHUNK / 32; ++st) {
            const v8h bf = __builtin_bit_cast(v8h, sb[(st * 32 + c) * 2 + g]);
            const v16f d = __builtin_amdgcn_mfma_f32_32x32x16_f16(a, bf, zc, 0, 0, 0);
#pragma unroll
            for (int r = 0; r < 16; ++r) rm[r] = fminf(rm[r], d[r]);
        }
    }

    // min over the 32 columns (lane&31); bit5 (g) untouched by masks <= 16
#pragma unroll
    for (int r = 0; r < 16; ++r) {
        float v = rm[r];
        v = fminf(v, __shfl_xor(v, 1));
        v = fminf(v, __shfl_xor(v, 2));
        v = fminf(v, __shfl_xor(v, 4));
        v = fminf(v, __shfl_xor(v, 8));
        v = fminf(v, __shfl_xor(v, 16));
        rm[r] = v;
    }
    if (c == 0) {
#pragma unroll
        for (int r = 0; r < 16; ++r) {
            const int rr = row0 + (r & 3) + 8 * (r >> 2) + 4 * g;  // verified C layout
            o[(size_t)b * Nq + rr] = rm[r];
        }
    }
}

// ---------------- fallback: round-3 identity-folded VALU kernel ----------------
constexpr int FTPB   = 256;
constexpr int FIPT   = 4;
constexpr int FTILE  = 512;
constexpr int FSPLIT = 8;

__global__ __launch_bounds__(FTPB, 4) void nnd_fold(
    const float* __restrict__ p1, const float* __restrict__ p2,
    float* __restrict__ out, int B, int N, int M)
{
    const int z   = blockIdx.z;
    const int dir = z / FSPLIT;
    const int s   = z % FSPLIT;
    const int b   = blockIdx.y;

    const float* __restrict__ q = dir ? p2 : p1;
    const float* __restrict__ r = dir ? p1 : p2;
    const int Nq = dir ? M : N;
    const int Nr = dir ? N : M;
    float* __restrict__ o = out + (dir ? (size_t)B * N : 0) + (size_t)b * Nq;

    const int tid = threadIdx.x;
    const float* qb = q + (size_t)b * Nq * 3;
    float qx[FIPT], qy[FIPT], qz[FIPT], qs[FIPT], mn[FIPT];
    int   qi[FIPT];
#pragma unroll
    for (int i = 0; i < FIPT; ++i) {
        qi[i] = blockIdx.x * (FTPB * FIPT) + i * FTPB + tid;
        if (qi[i] < Nq) {
            qx[i] = qb[qi[i] * 3 + 0]; qy[i] = qb[qi[i] * 3 + 1]; qz[i] = qb[qi[i] * 3 + 2];
        } else { qx[i] = qy[i] = qz[i] = 0.f; }
        float sq = qx[i] * qx[i];
        sq = fmaf(qy[i], qy[i], sq); sq = fmaf(qz[i], qz[i], sq);
        qs[i] = sq; mn[i] = 3.0e38f;
    }
    const int per = (Nr + FSPLIT - 1) / FSPLIT;
    const int r0 = s * per, r1 = min(Nr, r0 + per);
    __shared__ float4 shm[FTILE];
    const float* rb = r + (size_t)b * Nr * 3;
    for (int ts = r0; ts < r1; ts += FTILE) {
        const int npts = min(FTILE, r1 - ts);
        __syncthreads();
        if (npts == FTILE && ((((size_t)b * Nr + (size_t)ts) * 3) & 1) == 0) {
            const float2* src = (const float2*)(rb + (size_t)ts * 3);
            float2 a = src[3 * tid + 0], c2 = src[3 * tid + 1], e = src[3 * tid + 2];
            float s0 = a.x * a.x; s0 = fmaf(a.y, a.y, s0); s0 = fmaf(c2.x, c2.x, s0);
            float s1 = c2.y * c2.y; s1 = fmaf(e.x, e.x, s1); s1 = fmaf(e.y, e.y, s1);
            shm[2 * tid + 0] = make_float4(-2.f * a.x, -2.f * a.y, -2.f * c2.x, s0);
            shm[2 * tid + 1] = make_float4(-2.f * c2.y, -2.f * e.x, -2.f * e.y, s1);
        } else {
#pragma unroll
            for (int k = 0; k < 2; ++k) {
                const int pl = 2 * tid + k;
                float4 v = make_float4(0.f, 0.f, 0.f, 3.0e38f);
                if (pl < npts) {
                    const float* pp = rb + (size_t)(ts + pl) * 3;
                    float sq = pp[0] * pp[0];
                    sq = fmaf(pp[1], pp[1], sq); sq = fmaf(pp[2], pp[2], sq);
                    v = make_float4(-2.f * pp[0], -2.f * pp[1], -2.f * pp[2], sq);
                }
                shm[pl] = v;
            }
        }
        __syncthreads();
#pragma unroll 8
        for (int j = 0; j < FTILE; ++j) {
            const float4 p = shm[j];
#pragma unroll
            for (int i = 0; i < FIPT; ++i) {
                float t = fmaf(p.x, qx[i], p.w);
                t = fmaf(p.y, qy[i], t);
                t = fmaf(p.z, qz[i], t);
                mn[i] = fminf(mn[i], t);
            }
        }
    }
#pragma unroll
    for (int i = 0; i < FIPT; ++i)
        if (qi[i] < Nq) atomicMin((int*)&o[qi[i]], __float_as_int(mn[i] + qs[i]));
}

extern "C" void kernel_launch(void* const* d_in, const int* in_sizes, int n_in,
                              void* d_out, int out_size, void* d_ws, size_t ws_size,
                              hipStream_t stream) {
    const float* p1 = (const float*)d_in[0];
    const float* p2 = (const float*)d_in[1];
    float* out = (float*)d_out;

    const int B = 16;
    const int N = in_sizes[0] / (B * 3);
    const int M = in_sizes[1] / (B * 3);
    const int n1 = B * N, n2 = B * M;
    const size_t need = 64ull * (size_t)(n1 + n2);  // 4 fragment arrays, 32 B/point each x2 roles

    const bool mfma_ok = (N == M) && (N % RPB == 0) && (N % CHUNK == 0) && (ws_size >= need);

    if (mfma_ok) {
        const int total = n1 + n2;
        pack_pts<<<(total + MTPB - 1) / MTPB, MTPB, 0, stream>>>(p1, p2, (uint4*)d_ws, n1, n2);
        dim3 grid(N / RPB, B, 2);
        nnd_mfma<<<grid, MTPB, 0, stream>>>((const uint4*)d_ws, out, B, N, M);
    } else {
        hipMemsetAsync(d_out, 0x7f, (size_t)out_size * sizeof(float), stream);
        const int qmax = (N > M) ? N : M;
        dim3 grid((qmax + FTPB * FIPT - 1) / (FTPB * FIPT), B, 2 * FSPLIT);
        nnd_fold<<<grid, FTPB, 0, stream>>>(p1, p2, out, B, N, M);
    }
}